// Round 2
// baseline (933.567 us; speedup 1.0000x reference)
//
#include <hip/hip_runtime.h>

// Problem constants
#define G_GRAPHS 1024
#define N_NODES  40
#define M_EDGES  780          // N*(N-1)/2
#define NUM_NODES (G_GRAPHS * N_NODES)          // 40960
#define H_ELEMS  (NUM_NODES * 64)               // 2621440
#define X_STRIDE (4 * N_NODES)                  // 160
#define X_PER_G  (X_STRIDE * X_STRIDE)          // 25600

#define SLOPE 0.1f

__device__ __forceinline__ float lrelu(float v) {
    return fmaxf(v, SLOPE * v);
}

// ---------------------------------------------------------------------------
// K0: transpose Wn0 and We0 (64x64) into workspace so the MLP L1 dot can
// stream contiguous rows with uniform (scalar) loads.
// ---------------------------------------------------------------------------
__global__ __launch_bounds__(256) void k_prep(const float* __restrict__ Wn0,
                                              const float* __restrict__ We0,
                                              float* __restrict__ W0Tn,
                                              float* __restrict__ W0Te) {
    int t = blockIdx.x * 256 + threadIdx.x;   // 0..8191
    if (t < 4096) {
        int k = t >> 6, m = t & 63;
        W0Tn[k * 64 + m] = Wn0[m * 64 + k];
    } else {
        int t2 = t - 4096;
        int k = t2 >> 6, m = t2 & 63;
        W0Te[k * 64 + m] = We0[m * 64 + k];
    }
}

// ---------------------------------------------------------------------------
// K1: 3-layer GCN, one block per graph. Complete graph minus self-loops with
// deg==39 everywhere => aggregation = (colsum - own)/39 + b.
// Column sums now use all 256 threads (8-way node split + tree) instead of a
// 40-iteration serial loop on 32 threads.
// ---------------------------------------------------------------------------
__global__ __launch_bounds__(256) void k_gcn(const float* __restrict__ x,
                                             const float* __restrict__ Wg0,
                                             const float* __restrict__ bg0,
                                             const float* __restrict__ Wg1,
                                             const float* __restrict__ bg1,
                                             const float* __restrict__ Wg2,
                                             const float* __restrict__ bg2,
                                             float* __restrict__ hout) {
    __shared__ float h0[N_NODES * 6];
    __shared__ float buf[N_NODES * 64];
    __shared__ float S[64];
    __shared__ float P[8 * 64];      // partial column sums (8 node-groups)
    __shared__ float h1[N_NODES * 32];
    __shared__ float h2[N_NODES * 32];

    const int g = blockIdx.x;
    const int tid = threadIdx.x;
    const float inv39 = 1.0f / 39.0f;

    // load x[:, :6] for this graph's 40 nodes
    for (int idx = tid; idx < N_NODES * 6; idx += 256) {
        int n = idx / 6, f = idx - n * 6;
        h0[idx] = x[(g * N_NODES + n) * 16 + f];
    }
    __syncthreads();

    // ---- layer 0: (40x6)@(6x32) ----
    for (int idx = tid; idx < N_NODES * 32; idx += 256) {
        int n = idx >> 5, c = idx & 31;
        float s = 0.f;
#pragma unroll
        for (int f = 0; f < 6; f++) s += h0[n * 6 + f] * Wg0[f * 32 + c];
        buf[n * 32 + c] = s;
    }
    __syncthreads();
    {   // parallel colsum: 32 cols x 8 groups of 5 nodes
        int c = tid & 31, grp = tid >> 5;          // all 256 threads
        float s = 0.f;
#pragma unroll
        for (int n = grp * 5; n < grp * 5 + 5; n++) s += buf[n * 32 + c];
        P[grp * 32 + c] = s;
    }
    __syncthreads();
    if (tid < 32) {
        float s = 0.f;
#pragma unroll
        for (int grp = 0; grp < 8; grp++) s += P[grp * 32 + tid];
        S[tid] = s;
    }
    __syncthreads();
    for (int idx = tid; idx < N_NODES * 32; idx += 256) {
        int n = idx >> 5, c = idx & 31;
        float v = (S[c] - buf[n * 32 + c]) * inv39 + bg0[c];
        h1[idx] = lrelu(v);
    }
    __syncthreads();

    // ---- layer 1: (40x32)@(32x32) ----
    for (int idx = tid; idx < N_NODES * 32; idx += 256) {
        int n = idx >> 5, c = idx & 31;
        float s = 0.f;
#pragma unroll
        for (int m = 0; m < 32; m++) s += h1[n * 32 + m] * Wg1[m * 32 + c];
        buf[n * 32 + c] = s;
    }
    __syncthreads();
    {
        int c = tid & 31, grp = tid >> 5;
        float s = 0.f;
#pragma unroll
        for (int n = grp * 5; n < grp * 5 + 5; n++) s += buf[n * 32 + c];
        P[grp * 32 + c] = s;
    }
    __syncthreads();
    if (tid < 32) {
        float s = 0.f;
#pragma unroll
        for (int grp = 0; grp < 8; grp++) s += P[grp * 32 + tid];
        S[tid] = s;
    }
    __syncthreads();
    for (int idx = tid; idx < N_NODES * 32; idx += 256) {
        int n = idx >> 5, c = idx & 31;
        float v = (S[c] - buf[n * 32 + c]) * inv39 + bg1[c];
        h2[idx] = lrelu(v);
    }
    __syncthreads();

    // ---- layer 2: (40x32)@(32x64), linear ----
    for (int idx = tid; idx < N_NODES * 64; idx += 256) {
        int n = idx >> 6, c = idx & 63;
        float s = 0.f;
#pragma unroll
        for (int m = 0; m < 32; m++) s += h2[n * 32 + m] * Wg2[m * 64 + c];
        buf[idx] = s;
    }
    __syncthreads();
    {   // 64 cols x 4 groups of 10 nodes (256 threads)
        int c = tid & 63, grp = tid >> 6;          // grp 0..3
        float s = 0.f;
#pragma unroll
        for (int n = grp * 10; n < grp * 10 + 10; n++) s += buf[n * 64 + c];
        P[grp * 64 + c] = s;
    }
    __syncthreads();
    if (tid < 64) {
        float s = 0.f;
#pragma unroll
        for (int grp = 0; grp < 4; grp++) s += P[grp * 64 + tid];
        S[tid] = s;
    }
    __syncthreads();
    for (int idx = tid; idx < N_NODES * 64; idx += 256) {
        int n = idx >> 6, c = idx & 63;
        float v = (S[c] - buf[n * 64 + c]) * inv39 + bg2[c];
        hout[(g * N_NODES + n) * 64 + c] = v;
    }
}

// ---------------------------------------------------------------------------
// Shared MLP core: e[64] (regs) -> 64 -> 64 -> 10, weights via uniform loads.
// z1 is never materialized: each z1_k immediately fans out into acc[64].
// Requires ~150 live VGPRs -> callers must use __launch_bounds__(256, 3)
// (512/3 = 170 VGPR cap) so the allocator keeps e[] and acc[] in arch VGPRs.
// ---------------------------------------------------------------------------
__device__ __forceinline__ void mlp_64_64_10(const float e[64],
                                             const float* __restrict__ W0T,
                                             const float* __restrict__ b0,
                                             const float* __restrict__ W1,
                                             const float* __restrict__ b1,
                                             const float* __restrict__ W2,
                                             const float* __restrict__ b2,
                                             float ep[10]) {
    float acc[64];
#pragma unroll
    for (int j = 0; j < 64; j++) acc[j] = b1[j];

#pragma unroll 2
    for (int k = 0; k < 64; k++) {
        const float* w = W0T + k * 64;   // uniform address -> s_load
        float s0 = 0.f, s1 = 0.f, s2 = 0.f, s3 = 0.f;
#pragma unroll
        for (int m = 0; m < 64; m += 4) {
            s0 += e[m + 0] * w[m + 0];
            s1 += e[m + 1] * w[m + 1];
            s2 += e[m + 2] * w[m + 2];
            s3 += e[m + 3] * w[m + 3];
        }
        float z = (s0 + s1) + (s2 + s3) + b0[k];
        z = lrelu(z);
        const float* w1 = W1 + k * 64;   // uniform address -> s_load
#pragma unroll
        for (int j = 0; j < 64; j++) acc[j] += z * w1[j];
    }

#pragma unroll
    for (int t = 0; t < 10; t++) ep[t] = b2[t];
#pragma unroll
    for (int k = 0; k < 64; k++) {
        float z = lrelu(acc[k]);
        const float* w2 = W2 + k * 10;
#pragma unroll
        for (int t = 0; t < 10; t++) ep[t] += z * w2[t];
    }
}

__device__ __forceinline__ void make_block_rows(const float ep[10],
                                                float4& r0, float4& r1,
                                                float4& r2, float4& r3) {
    // SMAT_IDX = [0,1,2,3, 1,4,5,6, 2,5,7,8, 3,6,8,9]
    r0 = make_float4(ep[0], ep[1], ep[2], ep[3]);
    r1 = make_float4(ep[1], ep[4], ep[5], ep[6]);
    r2 = make_float4(ep[2], ep[5], ep[7], ep[8]);
    r3 = make_float4(ep[3], ep[6], ep[8], ep[9]);
}

// ---------------------------------------------------------------------------
// K2: node MLP (vp) -> diagonal 4x4 blocks of X. One thread per node.
// __launch_bounds__(256,3): 170 VGPR cap keeps e[]/acc[] in arch VGPRs.
// ---------------------------------------------------------------------------
__global__ __launch_bounds__(256, 3) void k_vp(const float* __restrict__ hg,
                                               const float* __restrict__ W0T,
                                               const float* __restrict__ b0,
                                               const float* __restrict__ W1,
                                               const float* __restrict__ b1,
                                               const float* __restrict__ W2,
                                               const float* __restrict__ b2,
                                               float* __restrict__ X) {
    int n = blockIdx.x * 256 + threadIdx.x;   // 0..40959, exact grid
    int g = n / N_NODES;
    int iloc = n - g * N_NODES;

    float e[64];
    const float4* hr = (const float4*)(hg + n * 64);
#pragma unroll
    for (int q = 0; q < 16; q++) {
        float4 v = hr[q];
        e[4 * q + 0] = v.x; e[4 * q + 1] = v.y;
        e[4 * q + 2] = v.z; e[4 * q + 3] = v.w;
    }

    float ep[10];
    mlp_64_64_10(e, W0T, b0, W1, b1, W2, b2, ep);

    float4 r0, r1, r2, r3;
    make_block_rows(ep, r0, r1, r2, r3);
    float* base = X + g * X_PER_G + (4 * iloc) * X_STRIDE + 4 * iloc;
    *(float4*)(base + 0 * X_STRIDE) = r0;
    *(float4*)(base + 1 * X_STRIDE) = r1;
    *(float4*)(base + 2 * X_STRIDE) = r2;
    *(float4*)(base + 3 * X_STRIDE) = r3;
}

// ---------------------------------------------------------------------------
// K3: edge MLP (ep) -> off-diagonal 4x4 blocks (i,j) and (j,i).
// One thread per upper-triangular edge; 1024*780 = 3120*256 exactly.
// __launch_bounds__(256,3): 170 VGPR cap keeps e[]/acc[] in arch VGPRs.
// ---------------------------------------------------------------------------
__global__ __launch_bounds__(256, 3) void k_edge(const float* __restrict__ hg,
                                                 const float* __restrict__ W0T,
                                                 const float* __restrict__ b0,
                                                 const float* __restrict__ W1,
                                                 const float* __restrict__ b1,
                                                 const float* __restrict__ W2,
                                                 const float* __restrict__ b2,
                                                 float* __restrict__ X) {
    int eid = blockIdx.x * 256 + threadIdx.x;   // 0..798719, exact grid
    int g = eid / M_EDGES;
    int m = eid - g * M_EDGES;

    // decode triu(N,1) pair (i,j) from linear index m
    int i = 0, rem = m;
    while (rem >= (N_NODES - 1) - i) { rem -= (N_NODES - 1) - i; ++i; }
    int j = i + 1 + rem;

    const float4* ha = (const float4*)(hg + (g * N_NODES + i) * 64);
    const float4* hb = (const float4*)(hg + (g * N_NODES + j) * 64);
    float e[64];
#pragma unroll
    for (int q = 0; q < 16; q++) {
        float4 a = ha[q], b = hb[q];
        e[4 * q + 0] = a.x + b.x; e[4 * q + 1] = a.y + b.y;
        e[4 * q + 2] = a.z + b.z; e[4 * q + 3] = a.w + b.w;
    }

    float ep[10];
    mlp_64_64_10(e, W0T, b0, W1, b1, W2, b2, ep);

    float4 r0, r1, r2, r3;
    make_block_rows(ep, r0, r1, r2, r3);

    float* Xg = X + g * X_PER_G;
    // block (i,j)
    float* p = Xg + (4 * i) * X_STRIDE + 4 * j;
    *(float4*)(p + 0 * X_STRIDE) = r0;
    *(float4*)(p + 1 * X_STRIDE) = r1;
    *(float4*)(p + 2 * X_STRIDE) = r2;
    *(float4*)(p + 3 * X_STRIDE) = r3;
    // block (j,i): the 4x4 block is symmetric, so same rows
    float* q2 = Xg + (4 * j) * X_STRIDE + 4 * i;
    *(float4*)(q2 + 0 * X_STRIDE) = r0;
    *(float4*)(q2 + 1 * X_STRIDE) = r1;
    *(float4*)(q2 + 2 * X_STRIDE) = r2;
    *(float4*)(q2 + 3 * X_STRIDE) = r3;
}

// ---------------------------------------------------------------------------
// Launch
// ---------------------------------------------------------------------------
extern "C" void kernel_launch(void* const* d_in, const int* in_sizes, int n_in,
                              void* d_out, int out_size, void* d_ws, size_t ws_size,
                              hipStream_t stream) {
    const float* x   = (const float*)d_in[0];
    // d_in[1] edge_index, d_in[2] ud_edges, d_in[3] edge_map: structure is
    // deterministic (complete graph, triu ordering) -> derived analytically.
    const float* Wg0 = (const float*)d_in[4];
    const float* bg0 = (const float*)d_in[5];
    const float* Wg1 = (const float*)d_in[6];
    const float* bg1 = (const float*)d_in[7];
    const float* Wg2 = (const float*)d_in[8];
    const float* bg2 = (const float*)d_in[9];
    const float* Wn0 = (const float*)d_in[10];
    const float* bn0 = (const float*)d_in[11];
    const float* Wn1 = (const float*)d_in[12];
    const float* bn1 = (const float*)d_in[13];
    const float* Wn2 = (const float*)d_in[14];
    const float* bn2 = (const float*)d_in[15];
    const float* We0 = (const float*)d_in[16];
    const float* be0 = (const float*)d_in[17];
    const float* We1 = (const float*)d_in[18];
    const float* be1 = (const float*)d_in[19];
    const float* We2 = (const float*)d_in[20];
    const float* be2 = (const float*)d_in[21];

    float* hout = (float*)d_out;            // h: 40960 x 64
    float* X    = hout + H_ELEMS;           // X: 1024 x 160 x 160

    float* W0Tn = (float*)d_ws;             // 4096 floats
    float* W0Te = W0Tn + 4096;              // 4096 floats

    k_prep<<<32, 256, 0, stream>>>(Wn0, We0, W0Tn, W0Te);
    k_gcn<<<G_GRAPHS, 256, 0, stream>>>(x, Wg0, bg0, Wg1, bg1, Wg2, bg2, hout);
    k_vp<<<NUM_NODES / 256, 256, 0, stream>>>(hout, W0Tn, bn0, Wn1, bn1, Wn2, bn2, X);
    k_edge<<<(G_GRAPHS * M_EDGES) / 256, 256, 0, stream>>>(hout, W0Te, be0, We1, be1, We2, be2, X);
}

// Round 3
// 239.627 us; speedup vs baseline: 3.8959x; 3.8959x over previous
//
#include <hip/hip_runtime.h>

// Problem constants
#define G_GRAPHS 1024
#define N_NODES  40
#define M_EDGES  780          // N*(N-1)/2
#define NUM_NODES (G_GRAPHS * N_NODES)          // 40960
#define H_ELEMS  (NUM_NODES * 64)               // 2621440
#define X_STRIDE 160
#define X_PER_G  25600
#define SLOPE 0.1f

#define EDGE_BLOCKS 6240      // 798720 / 128
#define VP_BLOCKS   320       // 40960 / 128
#define PACK_PER_MLP 9216     // W0(4096) + W1(4096) + W2(1024) bf16 elems

typedef __bf16 bf16x8 __attribute__((ext_vector_type(8)));
typedef unsigned short us8 __attribute__((ext_vector_type(8)));
typedef float f32x4 __attribute__((ext_vector_type(4)));

__device__ __forceinline__ float lrelu(float v) { return fmaxf(v, SLOPE * v); }
__device__ __forceinline__ unsigned short f2bf(float x) {
    __bf16 b = (__bf16)x;                       // RNE convert
    return __builtin_bit_cast(unsigned short, b);
}

// ---------------------------------------------------------------------------
// K0: pack MLP weights into MFMA B-fragment order (bf16) in d_ws.
// B-frag for mfma_f32_16x16x32_bf16: lane l holds B[k][n] with
//   n = nt*16 + (l&15), k = kt*32 + ((l>>4)&3)*8 + j, j=0..7 contiguous.
// Linear: ((nt*2+kt)*64 + l)*8 + j.  W2 padded 10->16 cols (zeros).
// Layout: [0..9215] edge MLP, [9216..18431] node MLP.
// ---------------------------------------------------------------------------
__global__ __launch_bounds__(256) void k_prep(const float* __restrict__ We0,
                                              const float* __restrict__ We1,
                                              const float* __restrict__ We2,
                                              const float* __restrict__ Wn0,
                                              const float* __restrict__ Wn1,
                                              const float* __restrict__ Wn2,
                                              unsigned short* __restrict__ wp) {
    int t = blockIdx.x * 256 + threadIdx.x;     // 0..18431 (72 blocks)
    int mlp = t / PACK_PER_MLP;
    int o = t - mlp * PACK_PER_MLP;
    const float* W0 = mlp ? Wn0 : We0;
    const float* W1 = mlp ? Wn1 : We1;
    const float* W2 = mlp ? Wn2 : We2;
    float val;
    if (o < 8192) {
        const float* W = (o < 4096) ? W0 : W1;
        int idx = o & 4095;
        int j = idx & 7, l = (idx >> 3) & 63, tt = idx >> 9;   // tt = nt*2+kt
        int kt = tt & 1, nt = tt >> 1;
        int k = kt * 32 + ((l >> 4) & 3) * 8 + j;
        int n = nt * 16 + (l & 15);
        val = W[k * 64 + n];
    } else {
        int idx = o - 8192;                      // 0..1023, nt=0 only
        int j = idx & 7, l = (idx >> 3) & 63, kt = idx >> 9;
        int k = kt * 32 + ((l >> 4) & 3) * 8 + j;
        int n = l & 15;
        val = (n < 10) ? W2[k * 10 + n] : 0.f;
    }
    wp[mlp * PACK_PER_MLP + o] = f2bf(val);
}

// ---------------------------------------------------------------------------
// K1: 3-layer GCN, one block per graph (unchanged fp32 path).
// deg==39 everywhere => aggregation = (colsum - own)/39 + b.
// ---------------------------------------------------------------------------
__global__ __launch_bounds__(256) void k_gcn(const float* __restrict__ x,
                                             const float* __restrict__ Wg0,
                                             const float* __restrict__ bg0,
                                             const float* __restrict__ Wg1,
                                             const float* __restrict__ bg1,
                                             const float* __restrict__ Wg2,
                                             const float* __restrict__ bg2,
                                             float* __restrict__ hout) {
    __shared__ float h0[N_NODES * 6];
    __shared__ float buf[N_NODES * 64];
    __shared__ float S[64];
    __shared__ float P[8 * 64];
    __shared__ float h1[N_NODES * 32];
    __shared__ float h2[N_NODES * 32];

    const int g = blockIdx.x;
    const int tid = threadIdx.x;
    const float inv39 = 1.0f / 39.0f;

    for (int idx = tid; idx < N_NODES * 6; idx += 256) {
        int n = idx / 6, f = idx - n * 6;
        h0[idx] = x[(g * N_NODES + n) * 16 + f];
    }
    __syncthreads();

    // layer 0
    for (int idx = tid; idx < N_NODES * 32; idx += 256) {
        int n = idx >> 5, c = idx & 31;
        float s = 0.f;
#pragma unroll
        for (int f = 0; f < 6; f++) s += h0[n * 6 + f] * Wg0[f * 32 + c];
        buf[n * 32 + c] = s;
    }
    __syncthreads();
    { int c = tid & 31, grp = tid >> 5; float s = 0.f;
#pragma unroll
      for (int n = grp * 5; n < grp * 5 + 5; n++) s += buf[n * 32 + c];
      P[grp * 32 + c] = s; }
    __syncthreads();
    if (tid < 32) { float s = 0.f;
#pragma unroll
      for (int grp = 0; grp < 8; grp++) s += P[grp * 32 + tid];
      S[tid] = s; }
    __syncthreads();
    for (int idx = tid; idx < N_NODES * 32; idx += 256) {
        int n = idx >> 5, c = idx & 31;
        h1[idx] = lrelu((S[c] - buf[n * 32 + c]) * inv39 + bg0[c]);
    }
    __syncthreads();

    // layer 1
    for (int idx = tid; idx < N_NODES * 32; idx += 256) {
        int n = idx >> 5, c = idx & 31;
        float s = 0.f;
#pragma unroll
        for (int m = 0; m < 32; m++) s += h1[n * 32 + m] * Wg1[m * 32 + c];
        buf[n * 32 + c] = s;
    }
    __syncthreads();
    { int c = tid & 31, grp = tid >> 5; float s = 0.f;
#pragma unroll
      for (int n = grp * 5; n < grp * 5 + 5; n++) s += buf[n * 32 + c];
      P[grp * 32 + c] = s; }
    __syncthreads();
    if (tid < 32) { float s = 0.f;
#pragma unroll
      for (int grp = 0; grp < 8; grp++) s += P[grp * 32 + tid];
      S[tid] = s; }
    __syncthreads();
    for (int idx = tid; idx < N_NODES * 32; idx += 256) {
        int n = idx >> 5, c = idx & 31;
        h2[idx] = lrelu((S[c] - buf[n * 32 + c]) * inv39 + bg1[c]);
    }
    __syncthreads();

    // layer 2
    for (int idx = tid; idx < N_NODES * 64; idx += 256) {
        int n = idx >> 6, c = idx & 63;
        float s = 0.f;
#pragma unroll
        for (int m = 0; m < 32; m++) s += h2[n * 32 + m] * Wg2[m * 64 + c];
        buf[idx] = s;
    }
    __syncthreads();
    { int c = tid & 63, grp = tid >> 6; float s = 0.f;
#pragma unroll
      for (int n = grp * 10; n < grp * 10 + 10; n++) s += buf[n * 64 + c];
      P[grp * 64 + c] = s; }
    __syncthreads();
    if (tid < 64) { float s = 0.f;
#pragma unroll
      for (int grp = 0; grp < 4; grp++) s += P[grp * 64 + tid];
      S[tid] = s; }
    __syncthreads();
    for (int idx = tid; idx < N_NODES * 64; idx += 256) {
        int n = idx >> 6, c = idx & 63;
        hout[(g * N_NODES + n) * 64 + c] = (S[c] - buf[n * 64 + c]) * inv39 + bg2[c];
    }
}

// ---------------------------------------------------------------------------
// K2: fused node+edge MLP via bf16 MFMA (16x16x32), 128 rows/block,
// fully wave-local (no __syncthreads): wave w owns rows 32w..32w+31 of
// sE/sZ/sEP through E-build -> GEMM1 -> GEMM2 -> GEMM3 -> scatter.
// LDS rows are 64 bf16 (128 B = exact bank wrap); 16-B chunks XOR-swizzled
// by (row&7) to spread banks.
// ---------------------------------------------------------------------------
__global__ __launch_bounds__(256) void k_mlp(const float* __restrict__ h,
                                             const unsigned short* __restrict__ wp,
                                             const float* __restrict__ be0,
                                             const float* __restrict__ be1,
                                             const float* __restrict__ be2,
                                             const float* __restrict__ bn0,
                                             const float* __restrict__ bn1,
                                             const float* __restrict__ bn2,
                                             float* __restrict__ X) {
    __shared__ __align__(16) unsigned short sE[128 * 64];   // E, later Z2
    __shared__ __align__(16) unsigned short sZ[128 * 64];   // Z1
    __shared__ __align__(16) float sEP[128 * 12];           // ep (10 used)

    const int tid = threadIdx.x;
    const int l = tid & 63;          // lane
    const int w = tid >> 6;          // wave 0..3
    const int bid = blockIdx.x;
    const bool is_edge = (bid < EDGE_BLOCKS);

    const unsigned short* wb = wp + (is_edge ? 0 : PACK_PER_MLP);
    const float* b0 = is_edge ? be0 : bn0;
    const float* b1 = is_edge ? be1 : bn1;
    const float* b2 = is_edge ? be2 : bn2;

    const int r = 32 * w + (l >> 1);   // this thread's row (E-build & scatter)
    const int hf = l & 1;              // feature half / scatter role
    int g, i = 0, j = 0;
    if (is_edge) {
        int eid = bid * 128 + r;
        g = eid / M_EDGES;
        int m = eid - g * M_EDGES;
        int rem = m;
        while (rem >= (N_NODES - 1) - i) { rem -= (N_NODES - 1) - i; ++i; }
        j = i + 1 + rem;
    } else {
        int nid = (bid - EDGE_BLOCKS) * 128 + r;
        g = nid / N_NODES;
        i = nid - g * N_NODES;
        j = i;
    }

    // ---- E build: row r, features [hf*32, hf*32+32) ----
    {
        const float4* pa = (const float4*)(h + (g * N_NODES + i) * 64 + hf * 32);
        const float4* pb = (const float4*)(h + (g * N_NODES + j) * 64 + hf * 32);
        unsigned short tmp[32];
#pragma unroll
        for (int q = 0; q < 8; q++) {
            float4 a = pa[q];
            if (is_edge) {
                float4 b = pb[q];
                a.x += b.x; a.y += b.y; a.z += b.z; a.w += b.w;
            }
            tmp[4 * q + 0] = f2bf(a.x); tmp[4 * q + 1] = f2bf(a.y);
            tmp[4 * q + 2] = f2bf(a.z); tmp[4 * q + 3] = f2bf(a.w);
        }
#pragma unroll
        for (int q = 0; q < 4; q++) {
            int cs = (hf * 4 + q) ^ (r & 7);
            *(us8*)((char*)sE + r * 128 + cs * 16) = *(const us8*)(tmp + 8 * q);
        }
    }

    const int col0 = l & 15, rq = (l >> 4) & 3;

    // A-fragment loader: A[m=lane&15][k=(lane>>4)*8+j]
    auto Afrag = [&](const unsigned short* s, int mt, int kt) -> bf16x8 {
        int row = 32 * w + mt * 16 + col0;
        int cs = (kt * 4 + rq) ^ (row & 7);
        return __builtin_bit_cast(bf16x8,
            *(const us8*)((const char*)s + row * 128 + cs * 16));
    };
    auto Bfrag = [&](const unsigned short* base, int tt) -> bf16x8 {
        return __builtin_bit_cast(bf16x8, *(const us8*)(base + (tt * 64 + l) * 8));
    };

    // ---- GEMM1: Z1 = lrelu(E @ W0 + b0), bf16 -> sZ ----
    {
        bf16x8 A[2][2];
#pragma unroll
        for (int mt = 0; mt < 2; mt++)
#pragma unroll
            for (int kt = 0; kt < 2; kt++) A[mt][kt] = Afrag(sE, mt, kt);
        f32x4 acc[2][4];
#pragma unroll
        for (int mt = 0; mt < 2; mt++)
#pragma unroll
            for (int nt = 0; nt < 4; nt++) acc[mt][nt] = (f32x4){0.f, 0.f, 0.f, 0.f};
#pragma unroll
        for (int nt = 0; nt < 4; nt++) {
            bf16x8 B0 = Bfrag(wb, nt * 2 + 0), B1 = Bfrag(wb, nt * 2 + 1);
#pragma unroll
            for (int mt = 0; mt < 2; mt++) {
                acc[mt][nt] = __builtin_amdgcn_mfma_f32_16x16x32_bf16(A[mt][0], B0, acc[mt][nt], 0, 0, 0);
                acc[mt][nt] = __builtin_amdgcn_mfma_f32_16x16x32_bf16(A[mt][1], B1, acc[mt][nt], 0, 0, 0);
            }
        }
#pragma unroll
        for (int nt = 0; nt < 4; nt++) {
            float bi = b0[nt * 16 + col0];
#pragma unroll
            for (int mt = 0; mt < 2; mt++)
#pragma unroll
                for (int reg = 0; reg < 4; reg++) {
                    int row = 32 * w + mt * 16 + rq * 4 + reg;
                    int col = nt * 16 + col0;
                    float z = lrelu(acc[mt][nt][reg] + bi);
                    int cs = (col >> 3) ^ (row & 7);
                    *(unsigned short*)((char*)sZ + row * 128 + cs * 16 + (col & 7) * 2) = f2bf(z);
                }
        }
    }

    // ---- GEMM2: Z2 = lrelu(Z1 @ W1 + b1), bf16 -> sE (reuse) ----
    {
        bf16x8 A[2][2];
#pragma unroll
        for (int mt = 0; mt < 2; mt++)
#pragma unroll
            for (int kt = 0; kt < 2; kt++) A[mt][kt] = Afrag(sZ, mt, kt);
        f32x4 acc[2][4];
#pragma unroll
        for (int mt = 0; mt < 2; mt++)
#pragma unroll
            for (int nt = 0; nt < 4; nt++) acc[mt][nt] = (f32x4){0.f, 0.f, 0.f, 0.f};
        const unsigned short* w1p = wb + 4096;
#pragma unroll
        for (int nt = 0; nt < 4; nt++) {
            bf16x8 B0 = Bfrag(w1p, nt * 2 + 0), B1 = Bfrag(w1p, nt * 2 + 1);
#pragma unroll
            for (int mt = 0; mt < 2; mt++) {
                acc[mt][nt] = __builtin_amdgcn_mfma_f32_16x16x32_bf16(A[mt][0], B0, acc[mt][nt], 0, 0, 0);
                acc[mt][nt] = __builtin_amdgcn_mfma_f32_16x16x32_bf16(A[mt][1], B1, acc[mt][nt], 0, 0, 0);
            }
        }
#pragma unroll
        for (int nt = 0; nt < 4; nt++) {
            float bi = b1[nt * 16 + col0];
#pragma unroll
            for (int mt = 0; mt < 2; mt++)
#pragma unroll
                for (int reg = 0; reg < 4; reg++) {
                    int row = 32 * w + mt * 16 + rq * 4 + reg;
                    int col = nt * 16 + col0;
                    float z = lrelu(acc[mt][nt][reg] + bi);
                    int cs = (col >> 3) ^ (row & 7);
                    *(unsigned short*)((char*)sE + row * 128 + cs * 16 + (col & 7) * 2) = f2bf(z);
                }
        }
    }

    // ---- GEMM3: EP = Z2 @ W2 + b2 (cols 0..9), fp32 -> sEP ----
    {
        bf16x8 A[2][2];
#pragma unroll
        for (int mt = 0; mt < 2; mt++)
#pragma unroll
            for (int kt = 0; kt < 2; kt++) A[mt][kt] = Afrag(sE, mt, kt);
        const unsigned short* w2p = wb + 8192;
        bf16x8 B0 = Bfrag(w2p, 0), B1 = Bfrag(w2p, 1);
        f32x4 acc[2];
#pragma unroll
        for (int mt = 0; mt < 2; mt++) {
            acc[mt] = (f32x4){0.f, 0.f, 0.f, 0.f};
            acc[mt] = __builtin_amdgcn_mfma_f32_16x16x32_bf16(A[mt][0], B0, acc[mt], 0, 0, 0);
            acc[mt] = __builtin_amdgcn_mfma_f32_16x16x32_bf16(A[mt][1], B1, acc[mt], 0, 0, 0);
        }
        if (col0 < 10) {
            float bz = b2[col0];
#pragma unroll
            for (int mt = 0; mt < 2; mt++)
#pragma unroll
                for (int reg = 0; reg < 4; reg++) {
                    int row = 32 * w + mt * 16 + rq * 4 + reg;
                    sEP[row * 12 + col0] = acc[mt][reg] + bz;
                }
        }
    }

    // ---- scatter: SMAT_IDX 4x4 block(s) for this thread's row ----
    {
        const float4* ev = (const float4*)(sEP + r * 12);
        float4 e0 = ev[0], e1 = ev[1], e2 = ev[2];
        float4 r0 = make_float4(e0.x, e0.y, e0.z, e0.w);
        float4 r1 = make_float4(e0.y, e1.x, e1.y, e1.z);
        float4 r2 = make_float4(e0.z, e1.y, e1.w, e2.x);
        float4 r3 = make_float4(e0.w, e1.z, e2.x, e2.y);
        float* Xg = X + g * X_PER_G;
        if (is_edge) {
            int bi = hf ? j : i, bj = hf ? i : j;   // (i,j) and (j,i); block symmetric
            float* p = Xg + (4 * bi) * X_STRIDE + 4 * bj;
            *(float4*)(p + 0 * X_STRIDE) = r0;
            *(float4*)(p + 1 * X_STRIDE) = r1;
            *(float4*)(p + 2 * X_STRIDE) = r2;
            *(float4*)(p + 3 * X_STRIDE) = r3;
        } else {
            float* p = Xg + (4 * i + hf * 2) * X_STRIDE + 4 * i;
            if (hf == 0) {
                *(float4*)(p + 0 * X_STRIDE) = r0;
                *(float4*)(p + 1 * X_STRIDE) = r1;
            } else {
                *(float4*)(p + 0 * X_STRIDE) = r2;
                *(float4*)(p + 1 * X_STRIDE) = r3;
            }
        }
    }
}

// ---------------------------------------------------------------------------
// Launch
// ---------------------------------------------------------------------------
extern "C" void kernel_launch(void* const* d_in, const int* in_sizes, int n_in,
                              void* d_out, int out_size, void* d_ws, size_t ws_size,
                              hipStream_t stream) {
    const float* x   = (const float*)d_in[0];
    const float* Wg0 = (const float*)d_in[4];
    const float* bg0 = (const float*)d_in[5];
    const float* Wg1 = (const float*)d_in[6];
    const float* bg1 = (const float*)d_in[7];
    const float* Wg2 = (const float*)d_in[8];
    const float* bg2 = (const float*)d_in[9];
    const float* Wn0 = (const float*)d_in[10];
    const float* bn0 = (const float*)d_in[11];
    const float* Wn1 = (const float*)d_in[12];
    const float* bn1 = (const float*)d_in[13];
    const float* Wn2 = (const float*)d_in[14];
    const float* bn2 = (const float*)d_in[15];
    const float* We0 = (const float*)d_in[16];
    const float* be0 = (const float*)d_in[17];
    const float* We1 = (const float*)d_in[18];
    const float* be1 = (const float*)d_in[19];
    const float* We2 = (const float*)d_in[20];
    const float* be2 = (const float*)d_in[21];

    float* hout = (float*)d_out;            // h: 40960 x 64 fp32
    float* X    = hout + H_ELEMS;           // X: 1024 x 160 x 160 fp32
    unsigned short* wp = (unsigned short*)d_ws;  // 18432 bf16 packed weights

    k_prep<<<72, 256, 0, stream>>>(We0, We1, We2, Wn0, Wn1, Wn2, wp);
    k_gcn<<<G_GRAPHS, 256, 0, stream>>>(x, Wg0, bg0, Wg1, bg1, Wg2, bg2, hout);
    k_mlp<<<EDGE_BLOCKS + VP_BLOCKS, 256, 0, stream>>>(hout, wp,
                                                       be0, be1, be2,
                                                       bn0, bn1, bn2, X);
}